// Round 2
// baseline (10281.037 us; speedup 1.0000x reference)
//
#include <hip/hip_runtime.h>
#include <stdint.h>

#define B_ 8
#define T_ 256
#define V_ 32000
#define E_ 768
#define N_ 1024
#define M_ (B_*T_)      // 2048 rows, m = b*T + t
#define RWG 16          // recurrence workgroups: 16 WGs x 4 waves x 16 cols = 1024 cols
#define LDK 40          // padded LDS row stride (ushorts) for GEMM tiles

typedef __attribute__((ext_vector_type(8))) short short8;
typedef __attribute__((ext_vector_type(4))) float floatx4;

__device__ __forceinline__ unsigned short f2b(float x) {
  union { float f; unsigned u; } v; v.f = x;
  unsigned r = v.u + 0x7fffu + ((v.u >> 16) & 1u);  // RNE
  return (unsigned short)(r >> 16);
}

// ---------- gather embedding rows -> bf16 (M x E) ----------
__global__ __launch_bounds__(256) void k_gather(const int* __restrict__ ids,
                                                const float* __restrict__ emb,
                                                unsigned short* __restrict__ xg) {
  int m = blockIdx.x;
  long tok = ids[m];
  const float* src = emb + tok * (long)E_;
  unsigned short* dst = xg + (long)m * E_;
  for (int e = threadIdx.x; e < E_; e += 256) dst[e] = f2b(src[e]);
}

// ---------- transpose fp32 (R x C) -> bf16 (C x R) ----------
__global__ __launch_bounds__(256) void k_transpose(const float* __restrict__ src,
                                                   unsigned short* __restrict__ dst,
                                                   int R, int C) {
  __shared__ float t[32][33];
  int tx = threadIdx.x & 31, ty = threadIdx.x >> 5;  // 32x8
  int c0 = blockIdx.x * 32, r0 = blockIdx.y * 32;
  #pragma unroll
  for (int i = 0; i < 32; i += 8)
    t[ty + i][tx] = src[(long)(r0 + ty + i) * C + c0 + tx];
  __syncthreads();
  #pragma unroll
  for (int i = 0; i < 32; i += 8)
    dst[(long)(c0 + ty + i) * R + r0 + tx] = f2b(t[tx][ty + i]);
}

// ---------- bf16 MFMA GEMM: C[MxN] = A[MxK] * BT[NxK]^T ----------
// 128x128 tile, 256 thr = 4 waves in 2x2, each wave 4x4 frags of 16x16x32.
// EPI: 0 = f32 out + bias[col]; 1 = bf16 out; 2 = f32 out
template<int EPI>
__global__ __launch_bounds__(256) void k_gemm_bt(const unsigned short* __restrict__ A,
                                                 const unsigned short* __restrict__ BT,
                                                 void* __restrict__ Cout,
                                                 const float* __restrict__ bias,
                                                 int M, int N, int K) {
  __shared__ unsigned short lsA[128 * LDK];
  __shared__ unsigned short lsB[128 * LDK];
  const int tid = threadIdx.x;
  const long m0 = (long)blockIdx.y * 128;
  const long n0 = (long)blockIdx.x * 128;
  const int w = tid >> 6, l = tid & 63;
  const int wm = (w >> 1) * 64, wn = (w & 1) * 64;
  const int lm = l & 15, kq = l >> 4;
  floatx4 acc[4][4] = {};
  for (int k0 = 0; k0 < K; k0 += 32) {
    #pragma unroll
    for (int i = 0; i < 2; ++i) {   // stage 128x32 of A and BT (dims divide exactly)
      int flat = i * 256 + tid;
      int r = flat >> 2, q4 = flat & 3;
      *(uint4*)(&lsA[r * LDK + q4 * 8]) = *(const uint4*)(&A[(m0 + r) * K + k0 + q4 * 8]);
      *(uint4*)(&lsB[r * LDK + q4 * 8]) = *(const uint4*)(&BT[(n0 + r) * K + k0 + q4 * 8]);
    }
    __syncthreads();
    short8 af[4], bf[4];
    #pragma unroll
    for (int mf = 0; mf < 4; ++mf) af[mf] = *(const short8*)(&lsA[(wm + mf * 16 + lm) * LDK + kq * 8]);
    #pragma unroll
    for (int nf = 0; nf < 4; ++nf) bf[nf] = *(const short8*)(&lsB[(wn + nf * 16 + lm) * LDK + kq * 8]);
    #pragma unroll
    for (int mf = 0; mf < 4; ++mf)
      #pragma unroll
      for (int nf = 0; nf < 4; ++nf)
        acc[mf][nf] = __builtin_amdgcn_mfma_f32_16x16x32_bf16(af[mf], bf[nf], acc[mf][nf], 0, 0, 0);
    __syncthreads();
  }
  // C/D layout (m89-verified): col = lane&15, row = (lane>>4)*4 + reg
  #pragma unroll
  for (int mf = 0; mf < 4; ++mf)
    #pragma unroll
    for (int nf = 0; nf < 4; ++nf)
      #pragma unroll
      for (int r = 0; r < 4; ++r) {
        long row = m0 + wm + mf * 16 + kq * 4 + r;
        long col = n0 + wn + nf * 16 + lm;
        float v = acc[mf][nf][r];
        if (EPI == 0)      ((float*)Cout)[row * N + col] = v + bias[col];
        else if (EPI == 1) ((unsigned short*)Cout)[row * N + col] = f2b(v);
        else               ((float*)Cout)[row * N + col] = v;
      }
}

// ---------- persistent recurrence: 1024 sequential (8x1024)@(1024x1024) + tanh ----------
// 16 WGs x 4 waves. Wave (g,w) owns 16 output columns [g*64+w*16, +16) with the FULL
// K=1024 slice of w_bb resident in 128 VGPRs (32 B-frags). No LDS, no __syncthreads in
// the step loop. Sync = 64 per-wave flags on separate 128B lines: release-fence + relaxed
// store by producer; all-lane parallel relaxed poll + one acquire fence by consumer.
__global__ __launch_bounds__(256, 1) void k_recurrence(const float* __restrict__ xbuf,
                                                       const float* __restrict__ w_bb,
                                                       const float* __restrict__ b_bb,
                                                       unsigned short* __restrict__ u0,
                                                       unsigned short* __restrict__ u1,
                                                       float* __restrict__ sAll,
                                                       unsigned* __restrict__ flags) {
  const int g = blockIdx.x;
  const int tid = threadIdx.x;
  const int w = tid >> 6, l = tid & 63;
  const int lm = l & 15, kq = l >> 4;
  const int c0 = g * 64 + w * 16;         // this wave's 16 output columns
  const int wid = g * 4 + w;              // global wave id, 0..63
  // --- one-time: load B-frags for cols c0..c0+15, K=0..1023 (B[n=lm][k=kq*8+j]) ---
  short8 bfrag[32];
  #pragma unroll
  for (int it = 0; it < 32; ++it) {
    short8 f;
    #pragma unroll
    for (int j = 0; j < 8; ++j)
      f[j] = (short)f2b(w_bb[(long)(it * 32 + kq * 8 + j) * N_ + c0 + lm]);
    bfrag[it] = f;
  }
  const float bias_r = b_bb[c0 + lm];
  // --- init state buffers for this wave's columns: rows 0..7 = x_{t=0}, rows 8..15 = 0 ---
  {
    int row = l >> 2, cb = (l & 3) * 4;   // 16 rows x 4 col-groups
    #pragma unroll
    for (int j = 0; j < 4; ++j) {
      int c = c0 + cb + j;
      unsigned short v0 = 0;
      if (row < 8) v0 = f2b(xbuf[((long)row * T_) * N_ + c]);
      u0[row * N_ + c] = v0;
      u1[row * N_ + c] = 0;
    }
  }
  __builtin_amdgcn_fence(__ATOMIC_RELEASE, "agent");
  if (l == 0) __hip_atomic_store(&flags[wid * 32], 1u, __ATOMIC_RELAXED, __HIP_MEMORY_SCOPE_AGENT);

  float xn[4] = {0.f, 0.f, 0.f, 0.f};
  for (int step = 0; step < 4 * T_; ++step) {
    // wait for all 64 waves to have published state for this step (lane l polls flag l)
    const unsigned tgt = (unsigned)step + 1u;
    while (__hip_atomic_load(&flags[l * 32], __ATOMIC_RELAXED, __HIP_MEMORY_SCOPE_AGENT) < tgt)
      __builtin_amdgcn_s_sleep(1);
    __builtin_amdgcn_fence(__ATOMIC_ACQUIRE, "agent");
    const unsigned short* __restrict__ src = (step & 1) ? u1 : u0;
    unsigned short*       __restrict__ dst = (step & 1) ? u0 : u1;
    const int t = step >> 2, ph = step & 3;
    // off-critical-path prefetch of the next pulse x[:, t+1]
    if (ph == 0 && l < 32 && t + 1 < T_) {
      #pragma unroll
      for (int r = 0; r < 4; ++r)
        xn[r] = xbuf[((long)((l >> 4) * 4 + r) * T_ + t + 1) * N_ + c0 + lm];
    }
    // matvec: acc[16x16] += u[16x1024] @ W[1024x16] (rows 8..15 are zero padding)
    floatx4 acc0 = {}, acc1 = {};
    #pragma unroll
    for (int it = 0; it < 32; it += 2) {
      short8 a0 = *(const short8*)(&src[lm * N_ + it * 32 + kq * 8]);
      short8 a1 = *(const short8*)(&src[lm * N_ + (it + 1) * 32 + kq * 8]);
      acc0 = __builtin_amdgcn_mfma_f32_16x16x32_bf16(a0, bfrag[it], acc0, 0, 0, 0);
      acc1 = __builtin_amdgcn_mfma_f32_16x16x32_bf16(a1, bfrag[it + 1], acc1, 0, 0, 0);
    }
    // epilogue: lanes 0..31 hold the 8 valid batch rows (row=(l>>4)*4+r, col=c0+lm)
    if (l < 32) {
      #pragma unroll
      for (int r = 0; r < 4; ++r) {
        int b = (l >> 4) * 4 + r;
        float sv = tanhf(acc0[r] + acc1[r] + bias_r);
        if (ph == 3) {
          sAll[((long)b * T_ + t) * N_ + c0 + lm] = sv;   // fp32 state for LN
          if (t + 1 < T_) sv += xn[r];                     // pulse inject
        }
        dst[b * N_ + c0 + lm] = f2b(sv);
      }
    }
    __builtin_amdgcn_fence(__ATOMIC_RELEASE, "agent");
    if (l == 0) __hip_atomic_store(&flags[wid * 32], (unsigned)step + 2u,
                                   __ATOMIC_RELAXED, __HIP_MEMORY_SCOPE_AGENT);
  }
}

// ---------- row layernorm (fp32 in, bf16 out) ----------
__global__ __launch_bounds__(256) void k_layernorm(const float* __restrict__ sAll,
                                                   const float* __restrict__ gamma,
                                                   const float* __restrict__ beta,
                                                   unsigned short* __restrict__ hln) {
  long m = blockIdx.x;
  const float* x = sAll + m * N_;
  float v[4], lsum = 0.f, lsq = 0.f;
  #pragma unroll
  for (int i = 0; i < 4; ++i) {
    v[i] = x[threadIdx.x + i * 256];
    lsum += v[i]; lsq += v[i] * v[i];
  }
  #pragma unroll
  for (int off = 32; off > 0; off >>= 1) {
    lsum += __shfl_down(lsum, off);
    lsq  += __shfl_down(lsq, off);
  }
  __shared__ float sa[4], sb[4];
  int w = threadIdx.x >> 6, l = threadIdx.x & 63;
  if (l == 0) { sa[w] = lsum; sb[w] = lsq; }
  __syncthreads();
  float tsum = sa[0] + sa[1] + sa[2] + sa[3];
  float tsq  = sb[0] + sb[1] + sb[2] + sb[3];
  float mean = tsum * (1.f / N_);
  float var  = tsq * (1.f / N_) - mean * mean;   // population var (ddof=0), matches jnp.var
  float rst  = rsqrtf(var + 1e-5f);
  #pragma unroll
  for (int i = 0; i < 4; ++i) {
    int n = threadIdx.x + i * 256;
    hln[m * N_ + n] = f2b((v[i] - mean) * rst * gamma[n] + beta[n]);
  }
}

extern "C" void kernel_launch(void* const* d_in, const int* in_sizes, int n_in,
                              void* d_out, int out_size, void* d_ws, size_t ws_size,
                              hipStream_t stream) {
  const int*   ids    = (const int*)d_in[0];
  const float* emb    = (const float*)d_in[1];
  const float* w_in   = (const float*)d_in[2];
  const float* b_in   = (const float*)d_in[3];
  const float* w_bb   = (const float*)d_in[4];
  const float* b_bb   = (const float*)d_in[5];
  const float* gamma  = (const float*)d_in[6];
  const float* beta   = (const float*)d_in[7];
  const float* w_out  = (const float*)d_in[8];
  const float* w_head = (const float*)d_in[9];
  float* out = (float*)d_out;

  char* p = (char*)d_ws;
  size_t off = 0;
  auto alloc = [&](size_t bytes) { void* r = p + off; off += (bytes + 255) & ~(size_t)255; return r; };
  unsigned*       flags   = (unsigned*)alloc(64 * 32 * 4);                 // per-wave sync flags (128B stride)
  unsigned short* xg      = (unsigned short*)alloc((size_t)M_ * E_ * 2);   // gathered emb, bf16
  unsigned short* w_inT   = (unsigned short*)alloc((size_t)N_ * E_ * 2);   // [N][E]
  unsigned short* w_outT  = (unsigned short*)alloc((size_t)E_ * N_ * 2);   // [E][N]
  unsigned short* w_headT = (unsigned short*)alloc((size_t)V_ * E_ * 2);   // [V][E]
  float*          xbuf    = (float*)alloc((size_t)M_ * N_ * 4);            // x = emb@w_in + b_in
  unsigned short* u0      = (unsigned short*)alloc(16 * N_ * 2);           // state ping
  unsigned short* u1      = (unsigned short*)alloc(16 * N_ * 2);           // state pong
  float*          sAll    = (float*)alloc((size_t)M_ * N_ * 4);            // final state per (b,t)
  unsigned short* hln     = (unsigned short*)alloc((size_t)M_ * N_ * 2);   // LN(s) bf16
  unsigned short* hw      = (unsigned short*)alloc((size_t)M_ * E_ * 2);   // h @ w_out bf16

  hipMemsetAsync(flags, 0, 64 * 32 * 4, stream);                           // flags = 0
  k_gather<<<M_, 256, 0, stream>>>(ids, emb, xg);
  k_transpose<<<dim3(N_ / 32, E_ / 32), 256, 0, stream>>>(w_in, w_inT, E_, N_);
  k_transpose<<<dim3(E_ / 32, N_ / 32), 256, 0, stream>>>(w_out, w_outT, N_, E_);
  k_transpose<<<dim3(V_ / 32, E_ / 32), 256, 0, stream>>>(w_head, w_headT, E_, V_);
  k_gemm_bt<0><<<dim3(N_ / 128, M_ / 128), 256, 0, stream>>>(xg, w_inT, xbuf, b_in, M_, N_, E_);
  k_recurrence<<<RWG, 256, 0, stream>>>(xbuf, w_bb, b_bb, u0, u1, sAll, flags);
  k_layernorm<<<M_, 256, 0, stream>>>(sAll, gamma, beta, hln);
  k_gemm_bt<1><<<dim3(E_ / 128, M_ / 128), 256, 0, stream>>>(hln, w_outT, hw, nullptr, M_, E_, N_);
  k_gemm_bt<2><<<dim3(V_ / 128, M_ / 128), 256, 0, stream>>>(hw, w_headT, out, nullptr, M_, V_, E_);
}